// Round 1
// baseline (710.501 us; speedup 1.0000x reference)
//
#include <hip/hip_runtime.h>

#define N_ROWS (512*256)        // 131072 rows
#define D 128
#define K 1024
#define TOTAL_ELEMS (N_ROWS*D)  // 16777216

// ws layout (floats): [0..K-1] = enorm (||e_k||^2), [K] = loss accumulator

__global__ void vq_enorm_kernel(const float* __restrict__ emb, float* __restrict__ enorm) {
    int k = blockIdx.x * blockDim.x + threadIdx.x;
    if (k < K) {
        float acc = 0.f;
        #pragma unroll
        for (int d = 0; d < D; ++d) {
            float e = emb[d * K + k];
            acc = fmaf(e, e, acc);
        }
        enorm[k] = acc;
    }
}

__global__ __launch_bounds__(256, 2) void vq_main_kernel(
        const float* __restrict__ x,
        const float* __restrict__ emb,
        const float* __restrict__ enorm,
        float* __restrict__ out,
        float* __restrict__ loss_acc) {
    const int n = blockIdx.x * 256 + threadIdx.x;

    // Load this thread's row into registers (32 x float4, statically indexed).
    float xr[D];
    const float4* xrow = reinterpret_cast<const float4*>(x + (size_t)n * D);
    #pragma unroll
    for (int i = 0; i < D / 4; ++i) {
        float4 v = xrow[i];
        xr[4*i+0] = v.x; xr[4*i+1] = v.y; xr[4*i+2] = v.z; xr[4*i+3] = v.w;
    }

    // argmin_k (enorm[k] - 2 * x.e_k)  — ||x||^2 term omitted (constant per row).
    float best = 3.4e38f;
    int bidx = 0;
    for (int k0 = 0; k0 < K; k0 += 8) {
        float acc[8];
        #pragma unroll
        for (int kk = 0; kk < 8; ++kk) acc[kk] = 0.f;
        #pragma unroll
        for (int d = 0; d < D; ++d) {
            const float xd = xr[d];
            #pragma unroll
            for (int kk = 0; kk < 8; ++kk)
                acc[kk] = fmaf(xd, emb[d * K + k0 + kk], acc[kk]);  // uniform addr -> s_load
        }
        #pragma unroll
        for (int kk = 0; kk < 8; ++kk) {
            float dist = fmaf(-2.f, acc[kk], enorm[k0 + kk]);
            if (dist < best) { best = dist; bidx = k0 + kk; }  // strict < : first-min tie-break
        }
    }

    // Gather winning codeword column, write quantized row, accumulate squared error.
    float sq = 0.f;
    float4* orow = reinterpret_cast<float4*>(out + (size_t)n * D);
    #pragma unroll
    for (int i = 0; i < D / 4; ++i) {
        float q0 = emb[(4*i+0) * K + bidx];
        float q1 = emb[(4*i+1) * K + bidx];
        float q2 = emb[(4*i+2) * K + bidx];
        float q3 = emb[(4*i+3) * K + bidx];
        float e0 = q0 - xr[4*i+0], e1 = q1 - xr[4*i+1];
        float e2 = q2 - xr[4*i+2], e3 = q3 - xr[4*i+3];
        sq = fmaf(e0, e0, sq); sq = fmaf(e1, e1, sq);
        sq = fmaf(e2, e2, sq); sq = fmaf(e3, e3, sq);
        orow[i] = make_float4(q0, q1, q2, q3);
    }

    // Block-level reduction of squared error, one atomic per block.
    #pragma unroll
    for (int off = 32; off > 0; off >>= 1)
        sq += __shfl_down(sq, off, 64);
    __shared__ float wsum[4];
    const int lane = threadIdx.x & 63;
    const int wid  = threadIdx.x >> 6;
    if (lane == 0) wsum[wid] = sq;
    __syncthreads();
    if (threadIdx.x == 0) {
        float s = wsum[0] + wsum[1] + wsum[2] + wsum[3];
        atomicAdd(loss_acc, s * (1.0f / (float)TOTAL_ELEMS));
    }
}

__global__ void vq_finalize_kernel(const float* __restrict__ loss_acc,
                                   float* __restrict__ out_losses) {
    if (threadIdx.x == 0) {
        float l = loss_acc[0];
        out_losses[0] = l;          // codebook_loss = mean((q - x)^2)
        out_losses[1] = 0.25f * l;  // commitment_loss = BETA * same value
    }
}

extern "C" void kernel_launch(void* const* d_in, const int* in_sizes, int n_in,
                              void* d_out, int out_size, void* d_ws, size_t ws_size,
                              hipStream_t stream) {
    const float* x   = (const float*)d_in[0];
    const float* emb = (const float*)d_in[1];
    float* out = (float*)d_out;

    float* enorm    = (float*)d_ws;   // K floats
    float* loss_acc = enorm + K;      // 1 float

    hipMemsetAsync(loss_acc, 0, sizeof(float), stream);
    vq_enorm_kernel<<<K / 256, 256, 0, stream>>>(emb, enorm);
    vq_main_kernel<<<N_ROWS / 256, 256, 0, stream>>>(x, emb, enorm, out, loss_acc);
    vq_finalize_kernel<<<1, 64, 0, stream>>>(loss_acc, out + (size_t)TOTAL_ELEMS);
}

// Round 3
// 215.747 us; speedup vs baseline: 3.2932x; 3.2932x over previous
//
#include <hip/hip_runtime.h>
#include <stdint.h>

#define NROWS (512*256)          // 131072
#define DDIM 128
#define KCB 1024
#define TOTALF (NROWS*DDIM)      // 16777216
#define TAU 0.25f                // refine gate: ~2500x the split-bf16 dist error tail

typedef __attribute__((ext_vector_type(8))) short short8v;
typedef __attribute__((ext_vector_type(4))) float f32x4;

__device__ __forceinline__ unsigned short bf16_rne(float f) {
    unsigned u = __builtin_bit_cast(unsigned, f);
    u += 0x7FFFu + ((u >> 16) & 1u);
    return (unsigned short)(u >> 16);
}
__device__ __forceinline__ float bf16_to_f32(unsigned short h) {
    unsigned u = ((unsigned)h) << 16;
    return __builtin_bit_cast(float, u);
}

// ---- prep: transpose emb[D][K] -> ebT[K][D] fp32 + bf16 hi/lo, and enorm ----
__global__ __launch_bounds__(256) void vq_prep(
    const float* __restrict__ emb,
    float* __restrict__ ebT_f32, short* __restrict__ ebT_hi,
    short* __restrict__ ebT_lo, float* __restrict__ enorm)
{
    __shared__ float tile[16][132];
    const int tid = threadIdx.x;
    const int kb = blockIdx.x * 16;
    const int rc = tid & 15;
    const int rd = tid >> 4;
    #pragma unroll
    for (int dd = 0; dd < 8; ++dd) {
        int d = dd * 16 + rd;
        tile[rc][d] = emb[(size_t)d * KCB + kb + rc];
    }
    __syncthreads();
    const int kl = tid >> 4;
    const int d0 = (tid & 15) * 8;
    const int kg = kb + kl;
    float sq = 0.f;
    short8v hv, lv; f32x4 fv0, fv1;
    #pragma unroll
    for (int j = 0; j < 8; ++j) {
        float f = tile[kl][d0 + j];
        unsigned short h = bf16_rne(f);
        float fh = bf16_to_f32(h);
        unsigned short lo = bf16_rne(f - fh);
        hv[j] = (short)h; lv[j] = (short)lo;
        if (j < 4) fv0[j] = f; else fv1[j - 4] = f;
        sq = fmaf(f, f, sq);
    }
    *(short8v*)(ebT_hi + (size_t)kg * DDIM + d0) = hv;
    *(short8v*)(ebT_lo + (size_t)kg * DDIM + d0) = lv;
    *(f32x4*)(ebT_f32 + (size_t)kg * DDIM + d0) = fv0;
    *(f32x4*)(ebT_f32 + (size_t)kg * DDIM + d0 + 4) = fv1;
    #pragma unroll
    for (int off = 1; off < 16; off <<= 1) sq += __shfl_xor(sq, off, 64);
    if ((tid & 15) == 0) enorm[kg] = sq;
}

// ---- main: 3-pass split-bf16 MFMA distances + fused top-2 argmin + refine ----
__global__ __launch_bounds__(256, 2) void vq_main_mfma(
    const float* __restrict__ x,
    const short* __restrict__ ebT_hi,
    const short* __restrict__ ebT_lo,
    const float* __restrict__ ebT_f32,
    const float* __restrict__ enorm,
    float* __restrict__ out,
    float* __restrict__ loss_acc)
{
    __shared__ char lds[32768];       // hi tile [0,16K), lo tile [16K,32K)
    const int tid  = threadIdx.x;
    const int wid  = tid >> 6;
    const int lane = tid & 63;
    const int c    = lane & 15;
    const int g    = lane >> 4;

    const size_t wave_row = ((size_t)blockIdx.x * 4 + wid) * 64;

    // A fragments (64 rows x 128 d, hi/lo). A layout: row=lane&15,
    // k = (lane>>4)*8 + j within each 32-k step (contiguous 8 per lane).
    short8v a_hi[4][4], a_lo[4][4];
    float xsq = 0.f;
    #pragma unroll
    for (int m = 0; m < 4; ++m) {
      #pragma unroll
      for (int s = 0; s < 4; ++s) {
        const float* src = x + (wave_row + m * 16 + c) * DDIM + s * 32 + g * 8;
        f32x4 v0 = *(const f32x4*)src;
        f32x4 v1 = *(const f32x4*)(src + 4);
        #pragma unroll
        for (int j = 0; j < 8; ++j) {
            float f = (j < 4) ? v0[j] : v1[j - 4];
            unsigned short h = bf16_rne(f);
            float fh = bf16_to_f32(h);
            unsigned short l = bf16_rne(f - fh);
            a_hi[m][s][j] = (short)h;
            a_lo[m][s][j] = (short)l;
            xsq = fmaf(f, f, xsq);
        }
      }
    }

    float best[4][4], sec[4][4];
    int   bidx[4][4], sidx[4][4];
    #pragma unroll
    for (int m = 0; m < 4; ++m)
      #pragma unroll
      for (int r = 0; r < 4; ++r) {
        best[m][r] = 3.4e38f; sec[m][r] = 3.4e38f;
        bidx[m][r] = 0; sidx[m][r] = 0;
      }

    for (int k0 = 0; k0 < KCB; k0 += 64) {
        // stage 64 cols x 128 d, hi (16 KB) + lo (16 KB), XOR-swizzled
        const char* ghb = (const char*)ebT_hi + (size_t)k0 * 256;
        const char* glb = (const char*)ebT_lo + (size_t)k0 * 256;
        short8v sh[4], sl[4];
        #pragma unroll
        for (int i = 0; i < 4; ++i)
            sh[i] = *(const short8v*)(ghb + i * 4096 + tid * 16);
        #pragma unroll
        for (int i = 0; i < 4; ++i)
            sl[i] = *(const short8v*)(glb + i * 4096 + tid * 16);
        __syncthreads();                  // prev chunk's compute done
        #pragma unroll
        for (int i = 0; i < 4; ++i) {
            int L = i * 4096 + tid * 16;
            int sw = ((L >> 8) & 7) << 4;
            *(short8v*)(lds + (L ^ sw)) = sh[i];
        }
        #pragma unroll
        for (int i = 0; i < 4; ++i) {
            int L = i * 4096 + tid * 16;
            int sw = ((L >> 8) & 7) << 4;
            *(short8v*)(lds + 16384 + (L ^ sw)) = sl[i];
        }
        __syncthreads();

        #pragma unroll
        for (int n = 0; n < 4; ++n) {
            const int col_local = n * 16 + c;
            const int cb = col_local << 8;
            const int sw = (c & 7) << 4;
            f32x4 acc[4];
            #pragma unroll
            for (int m = 0; m < 4; ++m) acc[m] = (f32x4){0.f, 0.f, 0.f, 0.f};
            #pragma unroll
            for (int s = 0; s < 4; ++s) {
                const int off = (cb + s * 64 + g * 16) ^ sw;
                short8v bh = *(const short8v*)(lds + off);
                short8v bl = *(const short8v*)(lds + 16384 + off);
                #pragma unroll
                for (int m = 0; m < 4; ++m)
                    acc[m] = __builtin_amdgcn_mfma_f32_16x16x32_bf16(a_hi[m][s], bh, acc[m], 0, 0, 0);
                #pragma unroll
                for (int m = 0; m < 4; ++m)
                    acc[m] = __builtin_amdgcn_mfma_f32_16x16x32_bf16(a_lo[m][s], bh, acc[m], 0, 0, 0);
                #pragma unroll
                for (int m = 0; m < 4; ++m)
                    acc[m] = __builtin_amdgcn_mfma_f32_16x16x32_bf16(a_hi[m][s], bl, acc[m], 0, 0, 0);
            }
            const int colg = k0 + col_local;
            const float en = enorm[colg];
            #pragma unroll
            for (int m = 0; m < 4; ++m)
              #pragma unroll
              for (int r = 0; r < 4; ++r) {
                float d = fmaf(-2.f, acc[m][r], en);      // ||x||^2 omitted
                bool lt  = d < best[m][r];
                bool lts = d < sec[m][r];
                sec[m][r]  = fminf(fmaxf(d, best[m][r]), sec[m][r]);   // med3 = 2nd-min
                sidx[m][r] = lt ? bidx[m][r] : (lts ? colg : sidx[m][r]);
                best[m][r] = lt ? d : best[m][r];
                bidx[m][r] = lt ? colg : bidx[m][r];
              }
        }
    }

    // cross-lane top-2 merge over the 16 col-lanes (disjoint candidate sets)
    #pragma unroll
    for (int m = 0; m < 4; ++m)
      #pragma unroll
      for (int r = 0; r < 4; ++r) {
        float b = best[m][r]; int i = bidx[m][r];
        float s2 = sec[m][r]; int j2 = sidx[m][r];
        #pragma unroll
        for (int off = 1; off < 16; off <<= 1) {
            float ob = __shfl_xor(b, off, 64);  int oi = __shfl_xor(i, off, 64);
            float os = __shfl_xor(s2, off, 64); int oj = __shfl_xor(j2, off, 64);
            bool take = (ob < b) || (ob == b && oi < i);
            float cb2 = take ? b : ob; int ci = take ? i : oi;    // demoted best
            b = take ? ob : b;         i = take ? oi : i;
            bool t1 = (os < s2) || (os == s2 && oj < j2);
            float s3 = t1 ? os : s2;   int j3 = t1 ? oj : j2;
            bool t2 = (cb2 < s3) || (cb2 == s3 && ci < j3);
            s2 = t2 ? cb2 : s3;        j2 = t2 ? ci : j3;
        }
        best[m][r] = b; bidx[m][r] = i; sec[m][r] = s2; sidx[m][r] = j2;
      }

    // exact fp32 refine where the approx gap is small (group-uniform branch)
    #pragma unroll
    for (int m = 0; m < 4; ++m)
      #pragma unroll
      for (int r = 0; r < 4; ++r) {
        if (sec[m][r] - best[m][r] < TAU) {
            const int ia = bidx[m][r], ib = sidx[m][r];
            const size_t row = wave_row + m * 16 + g * 4 + r;
            const f32x4* xp = (const f32x4*)(x + row * DDIM + c * 8);
            const f32x4* ea = (const f32x4*)(ebT_f32 + (size_t)ia * DDIM + c * 8);
            const f32x4* eb = (const f32x4*)(ebT_f32 + (size_t)ib * DDIM + c * 8);
            f32x4 x0 = xp[0], x1 = xp[1];
            f32x4 a0 = ea[0], a1 = ea[1];
            f32x4 b0 = eb[0], b1 = eb[1];
            float da = 0.f, db = 0.f;
            #pragma unroll
            for (int j = 0; j < 4; ++j) {
                da = fmaf(x0[j], a0[j], da); da = fmaf(x1[j], a1[j], da);
                db = fmaf(x0[j], b0[j], db); db = fmaf(x1[j], b1[j], db);
            }
            #pragma unroll
            for (int off = 1; off < 16; off <<= 1) {
                da += __shfl_xor(da, off, 64);
                db += __shfl_xor(db, off, 64);
            }
            float Da = fmaf(-2.f, da, enorm[ia]);
            float Db = fmaf(-2.f, db, enorm[ib]);
            bool flip = (Db < Da) || (Db == Da && ib < ia);
            if (flip) { bidx[m][r] = ib; best[m][r] = sec[m][r]; }
        }
      }

    // gather exact fp32 codewords, coalesced store
    #pragma unroll
    for (int m = 0; m < 4; ++m)
      #pragma unroll
      for (int r = 0; r < 4; ++r) {
        const size_t row = wave_row + m * 16 + g * 4 + r;
        const f32x4* qsrc = (const f32x4*)(ebT_f32 + (size_t)bidx[m][r] * DDIM + c * 8);
        f32x4* dst = (f32x4*)(out + row * DDIM + c * 8);
        dst[0] = qsrc[0];
        dst[1] = qsrc[1];
      }

    // loss: sum(||x||^2) + sum(best_dist) == sum((q-x)^2)
    float part = xsq;
    if (c == 0) {
        #pragma unroll
        for (int m = 0; m < 4; ++m)
          #pragma unroll
          for (int r = 0; r < 4; ++r) part += best[m][r];
    }
    #pragma unroll
    for (int off = 32; off > 0; off >>= 1) part += __shfl_down(part, off, 64);
    if (lane == 0) atomicAdd(loss_acc, part);
}

__global__ void vq_finalize(const float* __restrict__ loss_acc,
                            float* __restrict__ outl) {
    if (threadIdx.x == 0) {
        float l = loss_acc[0] * (1.0f / (float)TOTALF);
        outl[0] = l;           // codebook_loss
        outl[1] = 0.25f * l;   // commitment_loss = BETA * same value
    }
}

// ws layout: [0,512K) ebT_f32 | [512K,768K) ebT_hi | [768K,1M) ebT_lo
//            [1M,1M+4K) enorm | [1M+4K] loss_acc
extern "C" void kernel_launch(void* const* d_in, const int* in_sizes, int n_in,
                              void* d_out, int out_size, void* d_ws, size_t ws_size,
                              hipStream_t stream) {
    const float* x   = (const float*)d_in[0];
    const float* emb = (const float*)d_in[1];
    float* out = (float*)d_out;
    char* ws = (char*)d_ws;
    float* ebT_f32  = (float*)ws;
    short* ebT_hi   = (short*)(ws + 512 * 1024);
    short* ebT_lo   = (short*)(ws + 768 * 1024);
    float* enormp   = (float*)(ws + 1024 * 1024);
    float* loss_acc = (float*)(ws + 1024 * 1024 + 4096);

    hipMemsetAsync(loss_acc, 0, sizeof(float), stream);
    vq_prep<<<KCB / 16, 256, 0, stream>>>(emb, ebT_f32, ebT_hi, ebT_lo, enormp);
    vq_main_mfma<<<NROWS / 256, 256, 0, stream>>>(x, ebT_hi, ebT_lo, ebT_f32,
                                                  enormp, out, loss_acc);
    vq_finalize<<<1, 64, 0, stream>>>(loss_acc, out + (size_t)TOTALF);
}

// Round 5
// 126.420 us; speedup vs baseline: 5.6201x; 1.7066x over previous
//
#include <hip/hip_runtime.h>
#include <stdint.h>

#define NROWS (512*256)          // 131072
#define DDIM 128
#define KCB 1024
#define TOTALF (NROWS*DDIM)      // 16777216
#define TAU 0.35f                // refine gate vs 2nd-best gap (err 6sig~0.06 + 2*quant 0.016)
#define IDXMASK 0xFFFFFC00u      // clear low 10 mantissa bits for packed argmin keys

typedef __attribute__((ext_vector_type(8))) short short8v;
typedef __attribute__((ext_vector_type(4))) float f32x4;

static __device__ __forceinline__ unsigned short bf16_rne(float f) {
    unsigned u = __builtin_bit_cast(unsigned, f);
    u += 0x7FFFu + ((u >> 16) & 1u);
    return (unsigned short)(u >> 16);
}
static __device__ __forceinline__ float bf16_to_f32(unsigned short h) {
    unsigned u = ((unsigned)h) << 16;
    return __builtin_bit_cast(float, u);
}

// ---- prep: 64 blocks; block b -> chunk cidx=b>>2, col-group n=b&3 (16 cols).
// Outputs: ebT_f32[K][D], fragment-major bf16-hi blob, enorm.
__global__ __launch_bounds__(256) void vq_prep(
    const float* __restrict__ emb,
    float* __restrict__ ebT_f32,
    char* __restrict__ ebfrag,
    float* __restrict__ enorm)
{
    __shared__ float T[128 * 17];      // [d][c16], pad 17 kills bank conflicts
    __shared__ float red[256];
    const int t = threadIdx.x;
    const int cidx = blockIdx.x >> 2;
    const int n = blockIdx.x & 3;
    const int k0 = cidx * 64 + n * 16;          // first global col of this block
    {
        const int c16 = t & 15;
        const int dq = t >> 4;                  // 0..15
        #pragma unroll
        for (int i = 0; i < 8; ++i) {
            int d = dq * 8 + i;
            T[d * 17 + c16] = emb[(size_t)d * KCB + k0 + c16];
        }
    }
    __syncthreads();
    {   // enorm partials
        const int c16 = t & 15, part = t >> 4;
        float s = 0.f;
        #pragma unroll
        for (int i = 0; i < 8; ++i) { float v = T[(part*8+i)*17 + c16]; s = fmaf(v, v, s); }
        red[part * 16 + c16] = s;
    }
    {   // ebT_f32 [K][D] row-major (for refine dots + exact gather)
        const int col = t >> 4;                 // 0..15 local
        const int d0 = (t & 15) * 8;
        f32x4 w0, w1;
        #pragma unroll
        for (int j = 0; j < 4; ++j) w0[j] = T[(d0 + j) * 17 + col];
        #pragma unroll
        for (int j = 0; j < 4; ++j) w1[j] = T[(d0 + 4 + j) * 17 + col];
        *(f32x4*)(ebT_f32 + (size_t)(k0 + col) * DDIM + d0) = w0;
        *(f32x4*)(ebT_f32 + (size_t)(k0 + col) * DDIM + d0 + 4) = w1;
    }
    {   // fragment-major bf16 blob: chunk cidx, block (s,n), lane l -> 16B
        const int s = t >> 6, l = t & 63;
        const int cc = l & 15, g = l >> 4;
        const int d0 = s * 32 + g * 8;
        short8v hv;
        #pragma unroll
        for (int j = 0; j < 8; ++j) hv[j] = (short)bf16_rne(T[(d0 + j) * 17 + cc]);
        *(short8v*)(ebfrag + (size_t)cidx * 16384 + (s * 4 + n) * 1024 + l * 16) = hv;
    }
    __syncthreads();
    if (t < 16) {
        float s = 0.f;
        #pragma unroll
        for (int p = 0; p < 16; ++p) s += red[p * 16 + t];
        enorm[k0 + t] = s;
    }
}

// ---- main: no LDS, no barriers. 2-pass split-bf16 MFMA + packed top-3 argmin.
__global__ __launch_bounds__(256, 2) void vq_main(
    const float* __restrict__ x,
    const char* __restrict__ ebfrag,
    const float* __restrict__ ebT_f32,
    const float* __restrict__ enorm,
    float* __restrict__ out,
    float* __restrict__ loss_acc)
{
    const int tid = threadIdx.x, wid = tid >> 6, lane = tid & 63;
    const int c = lane & 15, g = lane >> 4;
    const size_t wave_row = ((size_t)blockIdx.x * 4 + wid) * 64;

    // A fragments: 64 rows x 128 d, split hi/lo (layout validated in round 3)
    short8v a_hi[4][4], a_lo[4][4];
    float xsq = 0.f;
    #pragma unroll
    for (int m = 0; m < 4; ++m) {
      #pragma unroll
      for (int s = 0; s < 4; ++s) {
        const float* src = x + (wave_row + m * 16 + c) * DDIM + s * 32 + g * 8;
        f32x4 v0 = *(const f32x4*)src;
        f32x4 v1 = *(const f32x4*)(src + 4);
        #pragma unroll
        for (int j = 0; j < 8; ++j) {
            float f = (j < 4) ? v0[j] : v1[j - 4];
            unsigned short h = bf16_rne(f);
            float fh = bf16_to_f32(h);
            a_hi[m][s][j] = (short)h;
            a_lo[m][s][j] = (short)bf16_rne(f - fh);
            xsq = fmaf(f, f, xsq);
        }
      }
    }

    // packed top-3 keys per (m,r): fp32 dist with col in low 10 mantissa bits
    float tb[4][4], ts2[4][4], tt[4][4];
    #pragma unroll
    for (int m = 0; m < 4; ++m)
      #pragma unroll
      for (int r = 0; r < 4; ++r) { tb[m][r] = 3.4e38f; ts2[m][r] = 3.4e38f; tt[m][r] = 3.4e38f; }

    for (int cidx = 0; cidx < 16; ++cidx) {
        const char* bb = ebfrag + (size_t)cidx * 16384;
        #pragma unroll
        for (int n = 0; n < 4; ++n) {
            short8v bh[4];
            #pragma unroll
            for (int s = 0; s < 4; ++s)
                bh[s] = *(const short8v*)(bb + (s * 4 + n) * 1024 + lane * 16);
            const int colv = cidx * 64 + n * 16 + c;
            const float en = enorm[colv];
            f32x4 acc[4];
            #pragma unroll
            for (int m = 0; m < 4; ++m) acc[m] = (f32x4){0.f, 0.f, 0.f, 0.f};
            #pragma unroll
            for (int s = 0; s < 4; ++s) {
                #pragma unroll
                for (int m = 0; m < 4; ++m)
                    acc[m] = __builtin_amdgcn_mfma_f32_16x16x32_bf16(a_hi[m][s], bh[s], acc[m], 0, 0, 0);
                #pragma unroll
                for (int m = 0; m < 4; ++m)
                    acc[m] = __builtin_amdgcn_mfma_f32_16x16x32_bf16(a_lo[m][s], bh[s], acc[m], 0, 0, 0);
            }
            #pragma unroll
            for (int m = 0; m < 4; ++m)
              #pragma unroll
              for (int r = 0; r < 4; ++r) {
                float d = fmaf(-2.f, acc[m][r], en);          // ||x||^2 omitted
                unsigned db = __builtin_bit_cast(unsigned, d);
                float key = __builtin_bit_cast(float, (db & IDXMASK) | (unsigned)colv);
                tt[m][r]  = __builtin_amdgcn_fmed3f(key, ts2[m][r], tt[m][r]);  // new 3rd
                ts2[m][r] = __builtin_amdgcn_fmed3f(key, tb[m][r],  ts2[m][r]); // new 2nd
                tb[m][r]  = fminf(key, tb[m][r]);                                // new 1st
              }
        }
    }

    // cross-lane top-3 merge over the 16 c-lanes (disjoint col sets)
    #pragma unroll
    for (int m = 0; m < 4; ++m)
      #pragma unroll
      for (int r = 0; r < 4; ++r) {
        float b = tb[m][r], s = ts2[m][r], t3 = tt[m][r];
        #pragma unroll
        for (int off = 1; off < 16; off <<= 1) {
            float ob = __shfl_xor(b, off, 64);
            float os = __shfl_xor(s, off, 64);
            float ot = __shfl_xor(t3, off, 64);
            t3 = __builtin_amdgcn_fmed3f(ob, s, t3);   // insert ob
            s  = __builtin_amdgcn_fmed3f(ob, b, s);
            b  = fminf(b, ob);
            t3 = __builtin_amdgcn_fmed3f(os, s, t3);   // insert os (os >= other b >= new b)
            s  = fminf(s, os);
            t3 = fminf(t3, ot);                        // insert ot (ot >= os >= new s)
        }
        tb[m][r] = b; ts2[m][r] = s; tt[m][r] = t3;
      }

    // refine: exact fp32 over top-3 where the 2ND-BEST gap is small (round-4 bug
    // was gating on the 3rd-best gap, leaving close best/second pairs unrefined)
    float lsum = 0.f;
    #pragma unroll
    for (int m = 0; m < 4; ++m)
      #pragma unroll
      for (int r = 0; r < 4; ++r) {
        unsigned b1 = __builtin_bit_cast(unsigned, tb[m][r]);
        unsigned b2 = __builtin_bit_cast(unsigned, ts2[m][r]);
        int chosen = (int)(b1 & 1023u);
        float dch = __builtin_bit_cast(float, b1 & IDXMASK);
        float d2a = __builtin_bit_cast(float, b2 & IDXMASK);
        const size_t row = wave_row + m * 16 + g * 4 + r;
        if (d2a - dch < TAU) {      // uniform within 16-lane group
            unsigned b3 = __builtin_bit_cast(unsigned, tt[m][r]);
            int i1 = chosen, i2 = (int)(b2 & 1023u), i3 = (int)(b3 & 1023u);
            const f32x4* xp = (const f32x4*)(x + row * DDIM + c * 8);
            f32x4 x0 = xp[0], x1 = xp[1];
            const f32x4* e1 = (const f32x4*)(ebT_f32 + (size_t)i1 * DDIM + c * 8);
            const f32x4* e2 = (const f32x4*)(ebT_f32 + (size_t)i2 * DDIM + c * 8);
            const f32x4* e3 = (const f32x4*)(ebT_f32 + (size_t)i3 * DDIM + c * 8);
            f32x4 p10 = e1[0], p11 = e1[1];
            f32x4 p20 = e2[0], p21 = e2[1];
            f32x4 p30 = e3[0], p31 = e3[1];
            float q1 = 0.f, q2 = 0.f, q3 = 0.f;
            #pragma unroll
            for (int j = 0; j < 4; ++j) {
                q1 = fmaf(x0[j], p10[j], q1); q1 = fmaf(x1[j], p11[j], q1);
                q2 = fmaf(x0[j], p20[j], q2); q2 = fmaf(x1[j], p21[j], q2);
                q3 = fmaf(x0[j], p30[j], q3); q3 = fmaf(x1[j], p31[j], q3);
            }
            #pragma unroll
            for (int off = 1; off < 16; off <<= 1) {
                q1 += __shfl_xor(q1, off, 64);
                q2 += __shfl_xor(q2, off, 64);
                q3 += __shfl_xor(q3, off, 64);
            }
            float D1 = fmaf(-2.f, q1, enorm[i1]);
            float D2 = fmaf(-2.f, q2, enorm[i2]);
            float D3 = fmaf(-2.f, q3, enorm[i3]);
            float bd = D1; int bi = i1;
            if (D2 < bd || (D2 == bd && i2 < bi)) { bd = D2; bi = i2; }
            if (D3 < bd || (D3 == bd && i3 < bi)) { bd = D3; bi = i3; }
            chosen = bi; dch = bd;
        }
        const f32x4* qsrc = (const f32x4*)(ebT_f32 + (size_t)chosen * DDIM + c * 8);
        f32x4* dst = (f32x4*)(out + row * DDIM + c * 8);
        dst[0] = qsrc[0];
        dst[1] = qsrc[1];
        if (c == 0) lsum += dch;    // dch uniform within group; count once
      }

    // loss: sum(||x||^2) + sum(best_dist) == sum((q-x)^2)
    float part = xsq + lsum;
    #pragma unroll
    for (int off = 32; off > 0; off >>= 1) part += __shfl_down(part, off, 64);
    if (lane == 0) atomicAdd(loss_acc, part);
}

__global__ void vq_finalize(const float* __restrict__ loss_acc,
                            float* __restrict__ outl) {
    if (threadIdx.x == 0) {
        float l = loss_acc[0] * (1.0f / (float)TOTALF);
        outl[0] = l;           // codebook_loss
        outl[1] = 0.25f * l;   // commitment_loss = BETA * same value
    }
}

// ws layout: [0,512K) ebT_f32 | [512K,768K) ebfrag (fragment-major bf16-hi)
//            [768K,772K) enorm | [772K] loss_acc     (~776 KB total)
extern "C" void kernel_launch(void* const* d_in, const int* in_sizes, int n_in,
                              void* d_out, int out_size, void* d_ws, size_t ws_size,
                              hipStream_t stream) {
    const float* x   = (const float*)d_in[0];
    const float* emb = (const float*)d_in[1];
    float* out = (float*)d_out;
    char* ws = (char*)d_ws;
    float* ebT_f32  = (float*)ws;
    char*  ebfrag   = ws + 512 * 1024;
    float* enormp   = (float*)(ws + 768 * 1024);
    float* loss_acc = (float*)(ws + 772 * 1024);

    hipMemsetAsync(loss_acc, 0, sizeof(float), stream);
    vq_prep<<<64, 256, 0, stream>>>(emb, ebT_f32, ebfrag, enormp);
    vq_main<<<NROWS / 256, 256, 0, stream>>>(x, ebfrag, ebT_f32, enormp, out, loss_acc);
    vq_finalize<<<1, 64, 0, stream>>>(loss_acc, out + (size_t)TOTALF);
}